// Round 15
// baseline (856.299 us; speedup 1.0000x reference)
//
#include <hip/hip_runtime.h>

static constexpr int Bn = 32, Sn = 64, Tn = 64, Hn = 512, Vn = 32000;
static constexpr int H3 = 1536;   // 3*H

typedef __attribute__((ext_vector_type(8))) short bf16x8;
typedef __attribute__((ext_vector_type(4))) float f32x4;

__device__ __forceinline__ short f2bf(float f) {
    unsigned u = __float_as_uint(f);
    u += 0x7FFFu + ((u >> 16) & 1u);   // round-to-nearest-even
    return (short)(u >> 16);
}
__device__ __forceinline__ float bf2f(short s) {
    return __uint_as_float(((unsigned)(unsigned short)s) << 16);
}

// async global->LDS, 16B per lane (dest must be linear in lane order)
__device__ __forceinline__ void gload16(const void* g, void* l) {
    __builtin_amdgcn_global_load_lds(
        (const __attribute__((address_space(1))) unsigned int*)g,
        (__attribute__((address_space(3))) unsigned int*)l, 16, 0, 0);
}

// ---------------- prep: merged convert of W_ih, W_hh, W_cc(full) + embedding gather ----------------
__global__ __launch_bounds__(256) void k_prep(const int* __restrict__ tgt,
                                              const float* __restrict__ emb,
                                              const float* __restrict__ W_ih,
                                              const float* __restrict__ W_hh,
                                              const float* __restrict__ W_cc,
                                              short* __restrict__ Xb,
                                              short* __restrict__ Wih_b, short* __restrict__ Whh_b,
                                              short* __restrict__ Wcc_b) {
    const int bid = blockIdx.x, tid = threadIdx.x;
    if (bid < 2048) {   // weight converts: 524288 units of 4 floats
        long u = (long)bid * 256 + tid;
        const float* src; short* dst;
        if (u < 196608)       { long e = u * 4;            src = W_ih + e; dst = Wih_b + e; }
        else if (u < 393216)  { long e = (u - 196608) * 4; src = W_hh + e; dst = Whh_b + e; }
        else                  { long e = (u - 393216) * 4; src = W_cc + e; dst = Wcc_b + e; }
        const float4 v = *(const float4*)src;
        short4 o; o.x = f2bf(v.x); o.y = f2bf(v.y); o.z = f2bf(v.z); o.w = f2bf(v.w);
        *(short4*)dst = o;
    } else {            // embedding gather: 2 rows per block
        const int m = (bid - 2048) * 2 + (tid >> 7);
        const int c = (tid & 127) * 4;
        const float4 v = *(const float4*)(emb + (long)tgt[m] * Hn + c);
        short4 o; o.x = f2bf(v.x); o.y = f2bf(v.y); o.z = f2bf(v.z); o.w = f2bf(v.w);
        *(short4*)(Xb + (long)m * Hn + c) = o;
    }
}

// ---------------- generic bf16 MFMA GEMM:  C[m][n] = sum_k A[m][k]*B[n][k] (+bias[n]) ----------------
__global__ __launch_bounds__(256) void k_gemm_bf16(const short* __restrict__ A, int lda,
                                                   const short* __restrict__ Bm, int ldb,
                                                   const float* __restrict__ bias,
                                                   float* __restrict__ C, int ldc, int K) {
    __shared__ short lA[4096];
    __shared__ short lB[4096];
    const int tid = threadIdx.x;
    const int row0 = blockIdx.y * 128;
    const int col0 = blockIdx.x * 128;
    const int lane = tid & 63;
    const int w = tid >> 6;
    const int wr = w >> 1, wc = w & 1;
    const int g = lane >> 4, rr = lane & 15;

    f32x4 acc[4][4];
    for (int m = 0; m < 4; ++m)
        for (int n = 0; n < 4; ++n)
            for (int q = 0; q < 4; ++q) acc[m][n][q] = 0.f;

    for (int kk = 0; kk < K; kk += 32) {
        for (int p = 0; p < 2; ++p) {
            int u = p * 256 + tid;
            int kg = u >> 7, r = u & 127;
            gload16(A + (long)(row0 + r) * lda + kk + kg * 8, &lA[u * 8]);
            gload16(Bm + (long)(col0 + r) * ldb + kk + kg * 8, &lB[u * 8]);
        }
        __syncthreads();
        bf16x8 av[4], bv[4];
        for (int m = 0; m < 4; ++m)
            av[m] = *(const bf16x8*)&lA[(g * 128 + wr * 64 + m * 16 + rr) * 8];
        for (int n = 0; n < 4; ++n)
            bv[n] = *(const bf16x8*)&lB[(g * 128 + wc * 64 + n * 16 + rr) * 8];
        for (int m = 0; m < 4; ++m)
            for (int n = 0; n < 4; ++n)
                acc[m][n] = __builtin_amdgcn_mfma_f32_16x16x32_bf16(av[m], bv[n], acc[m][n], 0, 0, 0);
        __syncthreads();
    }

    for (int n = 0; n < 4; ++n) {
        int gc = col0 + wc * 64 + n * 16 + rr;
        float bb = bias ? bias[gc] : 0.f;
        for (int m = 0; m < 4; ++m) {
            int gr = row0 + wr * 64 + m * 16 + g * 4;   // C/D: col=lane&15, row=4*(lane>>4)+q
            for (int q = 0; q < 4; ++q)
                C[(long)(gr + q) * ldc + gc] = acc[m][n][q] + bb;
        }
    }
}

// ---------------- per-row lse reduce + subtract (Cb is t-major; out is (b,t)-major f32) ----------------
__global__ __launch_bounds__(256) void k_sub(float* __restrict__ out, const short* __restrict__ Cb,
                                             const float* __restrict__ stats, int use_bf16) {
    const long row = blockIdx.x;                 // final row r = b*64+t
    const int tid = threadIdx.x;
    __shared__ float lse_s;
    if (tid < 64) {
        float m = -__builtin_inff(), s = 0.f;
        for (int tc = tid; tc < 250; tc += 64) {
            const float2 p = ((const float2*)stats)[row * 256 + tc];
            const float nm = fmaxf(m, p.x);
            s = s * __expf(m - nm) + p.y * __expf(p.x - nm);
            m = nm;
        }
        for (int o = 1; o < 64; o <<= 1) {
            const float om = __shfl_xor(m, o), os = __shfl_xor(s, o);
            const float nm = fmaxf(m, om);
            s = s * __expf(m - nm) + os * __expf(om - nm);
            m = nm;
        }
        if (tid == 0) lse_s = m + logf(s);
    }
    __syncthreads();
    const float lse = lse_s;
    float* p = out + row * (long)Vn;
    if (use_bf16) {
        const long rowp = (row & 63) * 32 + (row >> 6);   // t-major source row
        const short* cp = Cb + rowp * (long)Vn;
        for (int i = tid; i < Vn / 4; i += 256) {
            short4 c = *(const short4*)(cp + i * 4);
            float4 v;
            v.x = bf2f(c.x) - lse; v.y = bf2f(c.y) - lse;
            v.z = bf2f(c.z) - lse; v.w = bf2f(c.w) - lse;
            *(float4*)(p + i * 4) = v;
        }
    } else {
        for (int i = tid; i < Vn / 4; i += 256) {
            float4 v = *(const float4*)(p + i * 4);
            v.x -= lse; v.y -= lse; v.z -= lse; v.w -= lse;
            *(float4*)(p + i * 4) = v;
        }
    }
}

// ================= mega-kernel: recurrence + attn/ho + overlapped logits GEMM =================
// blocks 0..31:   GRU recurrence (h-slice partitioned)
// blocks 32..63:  attention + fused ho for batch b=bid-32; ho rows t-major; signal flagC[b]
// blocks 64..255: workers: convert W_out -> bf16, then logits tile-pairs gated on flagC
struct WSm3 {
    short h_all[Bn * Hn];      // frozen h, bf16, swizzled (32 KB)
    float gh_sl[3 * 16 * 32];  // gh slice (6 KB)
};
struct ASm3 {
    short encl[Sn * 520];      // enc[b] bf16 (66.6 KB)
    short Abuf[16 * 1032];     // [step%4 rows 0-3][ctx(512);hn(512)] padded (33 KB)
    float scp[8][64];
    float al[64];
};
struct GSm3 {
    short lA[2][4096];         // per-half staging (32 KB total)
    short lB[2][4096];
    float sml[2][128][2];
    float ssl[2][128][2];
};
union USm3 { WSm3 w; ASm3 a; GSm3 g; };

__device__ __forceinline__ void sig_flag(unsigned* slot, unsigned val) {
    asm volatile("s_waitcnt vmcnt(0)" ::: "memory");   // drain this wave's global stores
    __syncthreads();                                   // all waves drained
    if (threadIdx.x == 0)
        __hip_atomic_store(slot, val, __ATOMIC_RELAXED, __HIP_MEMORY_SCOPE_AGENT);
}
__device__ __forceinline__ void wait_flags32(const unsigned* base, unsigned need) {
    if (threadIdx.x < 32) {
        while (__hip_atomic_load(base + threadIdx.x * 32, __ATOMIC_RELAXED, __HIP_MEMORY_SCOPE_AGENT) < need)
            __builtin_amdgcn_s_sleep(1);
    }
    __syncthreads();
}

__global__ __launch_bounds__(512, 1) void k_seq(
    const float* __restrict__ GX, const int* __restrict__ fra,
    const float* __restrict__ h0,
    const short* __restrict__ Whh_b, const float* __restrict__ b_hh,
    const float* __restrict__ enc, const void* __restrict__ maskp,
    const short* __restrict__ Wcc_b, const float* __restrict__ b_cc,
    const float* __restrict__ W_out, short* __restrict__ Wout_b,
    const float* __restrict__ b_out,
    unsigned long long* __restrict__ hn_pk,    // [B*T][128] u64 (raw h_new)
    short* __restrict__ ho_b,                  // [T*B][512] bf16, t-major rows
    unsigned long long* __restrict__ hn_pub,   // [2][32][128] u64 (frozen h)
    unsigned* __restrict__ flags,              // [0..1024) W, [1024..2048) C, [2048..) V
    float* __restrict__ outF, short* __restrict__ Cb,
    float* __restrict__ stats, int use_bf16)
{
    __shared__ __align__(16) USm3 sm;
    const int bid = blockIdx.x;
    const int tid = threadIdx.x;
    const int wv = tid >> 6, lane = tid & 63;
    unsigned* flagW = flags;
    unsigned* flagC = flags + 1024;
    unsigned* flagV = flags + 2048;

    if (bid >= 64) {
        // ================= worker =================
        const int idx = bid - 64;   // 0..191
        // --- convert W_out f32 -> bf16 (cooperative, agent stores)
        for (int it = 0; it < 42; ++it) {
            long i = (long)it * 98304 + idx * 512 + tid;
            if (i < (long)Vn * Hn / 4) {
                const float4 v = *(const float4*)(W_out + i * 4);
                unsigned long long pk = (unsigned long long)(unsigned short)f2bf(v.x)
                                      | ((unsigned long long)(unsigned short)f2bf(v.y) << 16)
                                      | ((unsigned long long)(unsigned short)f2bf(v.z) << 32)
                                      | ((unsigned long long)(unsigned short)f2bf(v.w) << 48);
                __hip_atomic_store((unsigned long long*)(Wout_b + i * 4), pk,
                                   __ATOMIC_RELAXED, __HIP_MEMORY_SCOPE_AGENT);
            }
        }
        sig_flag(flagV + idx * 8, 1u);
        if (tid < 192) {
            while (__hip_atomic_load(flagV + tid * 8, __ATOMIC_RELAXED, __HIP_MEMORY_SCOPE_AGENT) < 1u)
                __builtin_amdgcn_s_sleep(1);
        }
        __syncthreads();

        // --- tile pairs: tau = 2p + half; 4000 tiles = 2000 pairs
        const int half = wv >> 2;          // 0/1
        const int tid2 = tid & 255;
        const int lane2 = tid2 & 63, w2 = tid2 >> 6;
        const int wr = w2 >> 1, wc = w2 & 1;
        const int g2 = lane2 >> 4, rr2 = lane2 & 15;

        for (int p = idx; p < 2000; p += 192) {
            const int tau = 2 * p + half;
            const int rtp = tau / 250, ct = tau % 250;
            const int rtmax = (2 * p + 1) / 250;
            wait_flags32(flagC, (unsigned)(rtmax + 1));
            const int row0 = rtp * 128;
            const int col0 = ct * 128;

            f32x4 acc[4][4];
            for (int m = 0; m < 4; ++m)
                for (int n = 0; n < 4; ++n)
                    for (int q = 0; q < 4; ++q) acc[m][n][q] = 0.f;

            for (int kk = 0; kk < 512; kk += 32) {
                for (int p2 = 0; p2 < 2; ++p2) {
                    int u = p2 * 256 + tid2;
                    int kg = u >> 7, r = u & 127;
                    gload16(ho_b + (long)(row0 + r) * 512 + kk + kg * 8, &sm.g.lA[half][u * 8]);
                    gload16(Wout_b + (long)(col0 + r) * 512 + kk + kg * 8, &sm.g.lB[half][u * 8]);
                }
                __syncthreads();
                bf16x8 av[4], bv[4];
                for (int m = 0; m < 4; ++m)
                    av[m] = *(const bf16x8*)&sm.g.lA[half][(g2 * 128 + wr * 64 + m * 16 + rr2) * 8];
                for (int n = 0; n < 4; ++n)
                    bv[n] = *(const bf16x8*)&sm.g.lB[half][(g2 * 128 + wc * 64 + n * 16 + rr2) * 8];
                for (int m = 0; m < 4; ++m)
                    for (int n = 0; n < 4; ++n)
                        acc[m][n] = __builtin_amdgcn_mfma_f32_16x16x32_bf16(av[m], bv[n], acc[m][n], 0, 0, 0);
                __syncthreads();
            }

            float bb[4];
            #pragma unroll
            for (int n = 0; n < 4; ++n) bb[n] = b_out[col0 + wc * 64 + n * 16 + rr2];

            #pragma unroll
            for (int n = 0; n < 4; ++n) {
                int gc = col0 + wc * 64 + n * 16 + rr2;
                #pragma unroll
                for (int m = 0; m < 4; ++m) {
                    int grp = row0 + wr * 64 + m * 16 + g2 * 4;   // t-major row'
                    #pragma unroll
                    for (int q = 0; q < 4; ++q) {
                        if (use_bf16) {
                            Cb[(long)(grp + q) * Vn + gc] = f2bf(acc[m][n][q] + bb[n]);
                        } else {
                            const int rp = grp + q;
                            const long fr = (long)(rp & 31) * 64 + (rp >> 5);
                            outF[fr * Vn + gc] = acc[m][n][q] + bb[n];
                        }
                    }
                }
            }
            #pragma unroll
            for (int m = 0; m < 4; ++m) {
                #pragma unroll
                for (int q = 0; q < 4; ++q) {
                    float mx = acc[m][0][q] + bb[0];
                    mx = fmaxf(mx, acc[m][1][q] + bb[1]);
                    mx = fmaxf(mx, acc[m][2][q] + bb[2]);
                    mx = fmaxf(mx, acc[m][3][q] + bb[3]);
                    mx = fmaxf(mx, __shfl_xor(mx, 1));
                    mx = fmaxf(mx, __shfl_xor(mx, 2));
                    mx = fmaxf(mx, __shfl_xor(mx, 4));
                    mx = fmaxf(mx, __shfl_xor(mx, 8));
                    float s = __expf(acc[m][0][q] + bb[0] - mx) + __expf(acc[m][1][q] + bb[1] - mx)
                            + __expf(acc[m][2][q] + bb[2] - mx) + __expf(acc[m][3][q] + bb[3] - mx);
                    s += __shfl_xor(s, 1);
                    s += __shfl_xor(s, 2);
                    s += __shfl_xor(s, 4);
                    s += __shfl_xor(s, 8);
                    if (rr2 == 0) {
                        const int r = wr * 64 + m * 16 + g2 * 4 + q;
                        sm.g.sml[half][r][wc] = mx; sm.g.ssl[half][r][wc] = s;
                    }
                }
            }
            __syncthreads();
            if (tid < 256) {
                const int h2 = tid >> 7, r = tid & 127;
                const int tau2 = 2 * p + h2;
                const int rowp = (tau2 / 250) * 128 + r;
                const int ct2 = tau2 % 250;
                const float m0 = sm.g.sml[h2][r][0], m1 = sm.g.sml[h2][r][1];
                const float mm = fmaxf(m0, m1);
                const float ss = sm.g.ssl[h2][r][0] * __expf(m0 - mm) + sm.g.ssl[h2][r][1] * __expf(m1 - mm);
                const long fr = (long)(rowp & 31) * 64 + (rowp >> 5);
                ((float2*)stats)[fr * 256 + ct2] = make_float2(mm, ss);
            }
            __syncthreads();
        }
        return;
    }

    if (bid >= Bn) {
        // ================= attention + fused ho =================
        const int b = bid - Bn;
        const unsigned w0 = ((const unsigned*)maskp)[0];
        const int mmode = (w0 == 1u) ? 0 : (w0 == 0x3F800000u ? 2 : 1);  // int32 / f32 / byte
        const int g = lane >> 4, rr = lane & 15;
        {   // enc[b] -> LDS bf16
            const float* encb = enc + (long)b * (Sn * Hn);
            #pragma unroll
            for (int it = 0; it < 16; ++it) {
                int e = (it * 512 + tid) * 4;
                float4 v = *(const float4*)(encb + e);
                int s = e >> 9, k = e & 511;
                short4 o; o.x = f2bf(v.x); o.y = f2bf(v.y); o.z = f2bf(v.z); o.w = f2bf(v.w);
                *(short4*)(sm.a.encl + s * 520 + k) = o;
            }
        }
        __syncthreads();
        for (int u = 0; u < Tn; ++u) {
            const int t4 = u & 3;
            wait_flags32(flagW, (unsigned)(u + 1));
            if (tid < 128) {   // stage raw h_new(u)[b] into Abuf[t4][512..]
                unsigned long long v = __hip_atomic_load(hn_pk + (long)(b * Tn + u) * 128 + tid,
                                                         __ATOMIC_RELAXED, __HIP_MEMORY_SCOPE_AGENT);
                *(unsigned long long*)&sm.a.Abuf[t4 * 1032 + 512 + tid * 4] = v;
            }
            __syncthreads();
            {   // score partials: wave `sub` covers k-slice, lane = s
                const int s = tid & 63, sub = tid >> 6;
                const short* erow = sm.a.encl + s * 520 + sub * 64;
                const short* hrow = sm.a.Abuf + t4 * 1032 + 512 + sub * 64;
                float p = 0.f;
                #pragma unroll
                for (int c8 = 0; c8 < 8; ++c8) {
                    bf16x8 ev = *(const bf16x8*)(erow + c8 * 8);
                    bf16x8 hv8 = *(const bf16x8*)(hrow + c8 * 8);
                    #pragma unroll
                    for (int e = 0; e < 8; ++e)
                        p += bf2f(ev[e]) * bf2f(hv8[e]);
                }
                sm.a.scp[sub][s] = p;
            }
            __syncthreads();
            if (tid < 64) {    // mask + softmax over S=64
                float v = 0.f;
                #pragma unroll
                for (int q = 0; q < 8; ++q) v += sm.a.scp[q][tid];
                bool mv;
                if (mmode == 0)      mv = ((const int*)maskp)[b * Sn + tid] != 0;
                else if (mmode == 1) mv = ((const unsigned char*)maskp)[b * Sn + tid] != 0;
                else                 mv = ((const float*)maskp)[b * Sn + tid] != 0.f;
                v = mv ? v : -__builtin_inff();
                float mx = v;
                for (int o = 1; o < 64; o <<= 1) mx = fmaxf(mx, __shfl_xor(mx, o));
                float e = __expf(v - mx);
                float su = e;
                for (int o = 1; o < 64; o <<= 1) su += __shfl_xor(su, o);
                sm.a.al[tid] = e / su;
            }
            __syncthreads();
            {   // ctx = sum_s al[s] * enc[b,s,:] -> Abuf[t4][0..512)
                float cx = 0.f;
                #pragma unroll 8
                for (int s = 0; s < 64; ++s)
                    cx += sm.a.al[s] * bf2f(sm.a.encl[s * 520 + tid]);
                sm.a.Abuf[t4 * 1032 + tid] = f2bf(cx);
            }
            if (t4 == 3) {
                __syncthreads();
                // ho for steps u-3..u: M=4 (rows 0-3 valid), N=512, K=1024; A=[ctx;hn], B=Wcc rows
                const int t0 = u - 3;
                #pragma unroll
                for (int ni = 0; ni < 4; ++ni) {
                    const int j0 = (wv * 4 + ni) * 16;
                    f32x4 acc = {0.f, 0.f, 0.f, 0.f};
                    for (int k = 0; k < 32; ++k) {
                        bf16x8 av = *(const bf16x8*)&sm.a.Abuf[rr * 1032 + k * 32 + g * 8];
                        bf16x8 bv = *(const bf16x8*)(Wcc_b + (long)(j0 + rr) * 1024 + k * 32 + g * 8);
                        acc = __builtin_amdgcn_mfma_f32_16x16x32_bf16(av, bv, acc, 0, 0, 0);
                    }
                    if (g == 0) {   // rows 0-3 live in g==0 lanes (row = 4*g + q)
                        const int j = j0 + rr;
                        const float bc = b_cc[j];
                        #pragma unroll
                        for (int q = 0; q < 4; ++q) {
                            const short hv = f2bf(tanhf(acc[q] + bc));
                            __hip_atomic_store(ho_b + (long)((t0 + q) * 32 + b) * 512 + j, hv,
                                               __ATOMIC_RELAXED, __HIP_MEMORY_SCOPE_AGENT);
                        }
                    }
                }
                sig_flag(flagC + b * 32, (unsigned)((u >> 2) + 1));
            }
        }
        return;
    }

    // ================= recurrence block =================
    bf16x8 afr[16];
    if (wv < 6) {          // gate g = wv>>1 (the two n-halves share A data)
        const int g = wv >> 1;
        const int row = g * 512 + bid * 16 + (lane & 15);
        #pragma unroll
        for (int k = 0; k < 16; ++k)
            afr[k] = *(const bf16x8*)(Whh_b + (long)row * 512 + k * 32 + (lane >> 4) * 8);
    }
    // h_all init from h0 (f32 -> bf16, swizzled)
    #pragma unroll
    for (int it = 0; it < 8; ++it) {
        const int idx2 = it * 512 + tid;          // 8B unit: b*128 + ci2
        const int b = idx2 >> 7, ci2 = idx2 & 127;
        const int j0 = ci2 * 4;
        const int soff = b * 512 + ((((ci2 >> 1)) ^ (b & 7)) << 3) + (ci2 & 1) * 4;
        const float4 v = *(const float4*)(h0 + b * 512 + j0);
        unsigned long long pk = (unsigned long long)(unsigned short)f2bf(v.x)
                              | ((unsigned long long)(unsigned short)f2bf(v.y) << 16)
                              | ((unsigned long long)(unsigned short)f2bf(v.z) << 32)
                              | ((unsigned long long)(unsigned short)f2bf(v.w) << 48);
        *(unsigned long long*)&sm.w.h_all[soff] = pk;
    }

    const int eb = tid >> 4, jj = tid & 15;       // elementwise mapping (batch, slice-col)
    float h_carry = h0[eb * 512 + bid * 16 + jj];
    const int flen_e = fra[eb];
    const int jglob = bid * 16 + jj;
    const float bhr = b_hh[jglob];
    const float bhz = b_hh[512 + jglob];
    const float bhn = b_hh[1024 + jglob];

    const int ci2s = wv * 16 + (lane & 15);       // this thread's staged 8B column
    const unsigned* fp = flagW + (ci2s >> 2) * 32;
    const int bbase = lane >> 4;

    for (int t = 0; t < Tn; ++t) {
        const long base = (long)(eb * Tn + t) * H3 + jglob;
        const float gxr = GX[base];
        const float gxz = GX[base + 512];
        const float gxn = GX[base + 1024];
        if (t >= 1) {
            while (__hip_atomic_load(fp, __ATOMIC_RELAXED, __HIP_MEMORY_SCOPE_AGENT) < (unsigned)t)
                __builtin_amdgcn_s_sleep(1);
            const unsigned long long* src = hn_pub + ((t - 1) & 1) * 4096;
            #pragma unroll
            for (int it = 0; it < 8; ++it) {
                const int b = bbase + it * 4;
                const unsigned long long v =
                    __hip_atomic_load(src + b * 128 + ci2s, __ATOMIC_RELAXED, __HIP_MEMORY_SCOPE_AGENT);
                const int soff = b * 512 + ((((ci2s >> 1)) ^ (b & 7)) << 3) + (ci2s & 1) * 4;
                *(unsigned long long*)&sm.w.h_all[soff] = v;
            }
        }
        __syncthreads();
        if (wv < 6) {
            const int g = wv >> 1, n = wv & 1;
            const int bq = n * 16 + (lane & 15);
            f32x4 a0 = {0.f, 0.f, 0.f, 0.f}, a1 = {0.f, 0.f, 0.f, 0.f};
            #pragma unroll
            for (int k = 0; k < 8; ++k) {
                const int c0 = k * 4 + (lane >> 4);
                const int c1 = (k + 8) * 4 + (lane >> 4);
                bf16x8 b0 = *(const bf16x8*)&sm.w.h_all[bq * 512 + ((c0 ^ (bq & 7)) << 3)];
                bf16x8 b1 = *(const bf16x8*)&sm.w.h_all[bq * 512 + ((c1 ^ (bq & 7)) << 3)];
                a0 = __builtin_amdgcn_mfma_f32_16x16x32_bf16(afr[k], b0, a0, 0, 0, 0);
                a1 = __builtin_amdgcn_mfma_f32_16x16x32_bf16(afr[k + 8], b1, a1, 0, 0, 0);
            }
            const int r0 = (lane >> 4) * 4;
            #pragma unroll
            for (int q = 0; q < 4; ++q)
                sm.w.gh_sl[g * 512 + (r0 + q) * 32 + bq] = a0[q] + a1[q];
        }
        __syncthreads();
        {
            const float ghr = sm.w.gh_sl[jj * 32 + eb]          + bhr;
            const float ghz = sm.w.gh_sl[512 + jj * 32 + eb]    + bhz;
            const float ghn = sm.w.gh_sl[1024 + jj * 32 + eb]   + bhn;
            const float r = 1.f / (1.f + __expf(-(gxr + ghr)));
            const float z = 1.f / (1.f + __expf(-(gxz + ghz)));
            const float nn = tanhf(gxn + r * ghn);
            const float hv = (1.f - z) * nn + z * h_carry;   // raw h_new (f32)
            h_carry = (t < flen_e) ? hv : h_carry;           // frozen state
            int f32w = (int)(unsigned short)f2bf(h_carry);
            int r32w = (int)(unsigned short)f2bf(hv);
            int f1 = __shfl_down(f32w, 1), f2 = __shfl_down(f32w, 2), f3 = __shfl_down(f32w, 3);
            int r1 = __shfl_down(r32w, 1), r2 = __shfl_down(r32w, 2), r3 = __shfl_down(r32w, 3);
            if ((jj & 3) == 0) {
                unsigned long long pkf = (unsigned long long)(unsigned)(f32w | (f1 << 16))
                                       | ((unsigned long long)(unsigned)(f2 | (f3 << 16)) << 32);
                unsigned long long pkr = (unsigned long long)(unsigned)(r32w | (r1 << 16))
                                       | ((unsigned long long)(unsigned)(r2 | (r3 << 16)) << 32);
                __hip_atomic_store(hn_pub + (t & 1) * 4096 + eb * 128 + bid * 4 + (jj >> 2), pkf,
                                   __ATOMIC_RELAXED, __HIP_MEMORY_SCOPE_AGENT);
                __hip_atomic_store(hn_pk + (long)(eb * Tn + t) * 128 + bid * 4 + (jj >> 2), pkr,
                                   __ATOMIC_RELAXED, __HIP_MEMORY_SCOPE_AGENT);
            }
            sig_flag(flagW + bid * 32, (unsigned)(t + 1));
        }
    }
}

extern "C" void kernel_launch(void* const* d_in, const int* in_sizes, int n_in,
                              void* d_out, int out_size, void* d_ws, size_t ws_size,
                              hipStream_t stream) {
    const float* enc   = (const float*)d_in[0];
    const float* h0    = (const float*)d_in[1];
    const void*  maskp = d_in[2];
    const int*   tgt   = (const int*)d_in[3];
    const int*   fra   = (const int*)d_in[4];
    const float* emb   = (const float*)d_in[5];
    const float* W_ih  = (const float*)d_in[6];
    const float* W_hh  = (const float*)d_in[7];
    const float* b_ih  = (const float*)d_in[8];
    const float* b_hh  = (const float*)d_in[9];
    const float* W_cc  = (const float*)d_in[10];
    const float* b_cc  = (const float*)d_in[11];
    const float* W_out = (const float*)d_in[12];
    const float* b_out = (const float*)d_in[13];
    float* out = (float*)d_out;

    char* ws = (char*)d_ws;
    float*    GX      = (float*)ws;   ws += (long)2048 * 1536 * 4;  // 12.58 MB
    short*    Xb      = (short*)ws;   ws += (long)2048 * 512 * 2;   //  2.10 MB
    short*    Wih_b   = (short*)ws;   ws += (long)1536 * 512 * 2;   //  1.57 MB
    short*    Wout_b  = (short*)ws;   ws += (long)32000 * 512 * 2;  // 32.77 MB
    short*    Whh_b   = (short*)ws;   ws += (long)1536 * 512 * 2;   //  1.57 MB
    short*    Wcc_b   = (short*)ws;   ws += (long)512 * 1024 * 2;   //  1.05 MB
    short*    ho_b    = (short*)ws;   ws += (long)2048 * 512 * 2;   //  2.10 MB (t-major)
    short*    hn_pk_s = (short*)ws;   ws += (long)2048 * 512 * 2;   //  2.10 MB
    float*    stats   = (float*)ws;   ws += (long)2048 * 256 * 2 * 4; // 4.19 MB
    unsigned long long* hn_pub = (unsigned long long*)ws; ws += (long)2 * 4096 * 8;   // 64 KB
    unsigned* flags   = (unsigned*)ws; ws += 16384;                 // 16 KB: W/C/V
    const long cb_bytes = (long)2048 * Vn * 2;                      // 131 MB bf16 C
    const long used = (long)(ws - (char*)d_ws);
    const int use_bf16 = (ws_size >= (size_t)(used + cb_bytes)) ? 1 : 0;
    short* Cb = use_bf16 ? (short*)ws : nullptr;

    hipMemsetAsync(flags, 0, 16384, stream);
    k_prep<<<3072, 256, 0, stream>>>(tgt, emb, W_ih, W_hh, W_cc, Xb, Wih_b, Whh_b, Wcc_b);

    // --- GX = X @ W_ih^T + b_ih   (M=2048, N=1536, K=512)
    k_gemm_bf16<<<dim3(12, 16), 256, 0, stream>>>(Xb, 512, Wih_b, 512, b_ih, GX, 1536, 512);

    // --- mega: recurrence (0-31) + attn/ho (32-63) + logits workers (64-255)
    k_seq<<<256, 512, 0, stream>>>(GX, fra, h0, Whh_b, b_hh, enc, maskp,
                                   Wcc_b, b_cc, W_out, Wout_b, b_out,
                                   (unsigned long long*)hn_pk_s, ho_b, hn_pub, flags,
                                   out, Cb, stats, use_bf16);

    // --- per-row lse reduce + subtract -> f32 d_out
    k_sub<<<2048, 256, 0, stream>>>(out, Cb, stats, use_bf16);
}

// Round 16
// 665.478 us; speedup vs baseline: 1.2867x; 1.2867x over previous
//
#include <hip/hip_runtime.h>

static constexpr int Bn = 32, Sn = 64, Tn = 64, Hn = 512, Vn = 32000;
static constexpr int H3 = 1536;   // 3*H

typedef __attribute__((ext_vector_type(8))) short bf16x8;
typedef __attribute__((ext_vector_type(4))) float f32x4;

__device__ __forceinline__ short f2bf(float f) {
    unsigned u = __float_as_uint(f);
    u += 0x7FFFu + ((u >> 16) & 1u);   // round-to-nearest-even
    return (short)(u >> 16);
}
__device__ __forceinline__ float bf2f(short s) {
    return __uint_as_float(((unsigned)(unsigned short)s) << 16);
}

// async global->LDS, 16B per lane (dest must be linear in lane order)
__device__ __forceinline__ void gload16(const void* g, void* l) {
    __builtin_amdgcn_global_load_lds(
        (const __attribute__((address_space(1))) unsigned int*)g,
        (__attribute__((address_space(3))) unsigned int*)l, 16, 0, 0);
}

// ---------------- prep: merged convert of W_ih, W_hh, Wc1, Wc2 + embedding gather ----------------
__global__ __launch_bounds__(256) void k_prep(const int* __restrict__ tgt,
                                              const float* __restrict__ emb,
                                              const float* __restrict__ W_ih,
                                              const float* __restrict__ W_hh,
                                              const float* __restrict__ W_cc,
                                              short* __restrict__ Xb,
                                              short* __restrict__ Wih_b, short* __restrict__ Whh_b,
                                              short* __restrict__ Wc1_b, short* __restrict__ Wc2_b) {
    const int bid = blockIdx.x, tid = threadIdx.x;
    if (bid < 2048) {   // weight converts: 524288 units of 4 floats
        long u = (long)bid * 256 + tid;
        const float* src; short* dst;
        if (u < 196608)       { long e = u * 4;            src = W_ih + e; dst = Wih_b + e; }
        else if (u < 393216)  { long e = (u - 196608) * 4; src = W_hh + e; dst = Whh_b + e; }
        else if (u < 458752)  { long e = (u - 393216) * 4; long r = e >> 9; int c = (int)(e & 511);
                                src = W_cc + r * 1024 + c;       dst = Wc1_b + e; }
        else                  { long e = (u - 458752) * 4; long r = e >> 9; int c = (int)(e & 511);
                                src = W_cc + r * 1024 + 512 + c; dst = Wc2_b + e; }
        const float4 v = *(const float4*)src;
        short4 o; o.x = f2bf(v.x); o.y = f2bf(v.y); o.z = f2bf(v.z); o.w = f2bf(v.w);
        *(short4*)dst = o;
    } else {            // embedding gather: 2 rows per block
        const int m = (bid - 2048) * 2 + (tid >> 7);
        const int c = (tid & 127) * 4;
        const float4 v = *(const float4*)(emb + (long)tgt[m] * Hn + c);
        short4 o; o.x = f2bf(v.x); o.y = f2bf(v.y); o.z = f2bf(v.z); o.w = f2bf(v.w);
        *(short4*)(Xb + (long)m * Hn + c) = o;
    }
}

// ---------------- generic bf16 MFMA GEMM:  C[m][n] = sum_k A[m][k]*B[n][k] (+bias[n]) ----------------
__global__ __launch_bounds__(256) void k_gemm_bf16(const short* __restrict__ A, int lda,
                                                   const short* __restrict__ Bm, int ldb,
                                                   const float* __restrict__ bias,
                                                   float* __restrict__ C, int ldc, int K) {
    __shared__ short lA[4096];
    __shared__ short lB[4096];
    const int tid = threadIdx.x;
    const int row0 = blockIdx.y * 128;
    const int col0 = blockIdx.x * 128;
    const int lane = tid & 63;
    const int w = tid >> 6;
    const int wr = w >> 1, wc = w & 1;
    const int g = lane >> 4, rr = lane & 15;

    f32x4 acc[4][4];
    for (int m = 0; m < 4; ++m)
        for (int n = 0; n < 4; ++n)
            for (int q = 0; q < 4; ++q) acc[m][n][q] = 0.f;

    for (int kk = 0; kk < K; kk += 32) {
        for (int p = 0; p < 2; ++p) {
            int u = p * 256 + tid;
            int kg = u >> 7, r = u & 127;
            gload16(A + (long)(row0 + r) * lda + kk + kg * 8, &lA[u * 8]);
            gload16(Bm + (long)(col0 + r) * ldb + kk + kg * 8, &lB[u * 8]);
        }
        __syncthreads();
        bf16x8 av[4], bv[4];
        for (int m = 0; m < 4; ++m)
            av[m] = *(const bf16x8*)&lA[(g * 128 + wr * 64 + m * 16 + rr) * 8];
        for (int n = 0; n < 4; ++n)
            bv[n] = *(const bf16x8*)&lB[(g * 128 + wc * 64 + n * 16 + rr) * 8];
        for (int m = 0; m < 4; ++m)
            for (int n = 0; n < 4; ++n)
                acc[m][n] = __builtin_amdgcn_mfma_f32_16x16x32_bf16(av[m], bv[n], acc[m][n], 0, 0, 0);
        __syncthreads();
    }

    for (int n = 0; n < 4; ++n) {
        int gc = col0 + wc * 64 + n * 16 + rr;
        float bb = bias ? bias[gc] : 0.f;
        for (int m = 0; m < 4; ++m) {
            int gr = row0 + wr * 64 + m * 16 + g * 4;   // C/D: col=lane&15, row=4*(lane>>4)+q
            for (int q = 0; q < 4; ++q)
                C[(long)(gr + q) * ldc + gc] = acc[m][n][q] + bb;
        }
    }
}

// ---------------- logits GEMM with fused per-tile logsumexp stats ----------------
// 1D grid 4000, col-tile-major: 16 consecutive blocks share one Wout col tile (L2 reuse).
__global__ __launch_bounds__(256) void k_gemm_logits(const short* __restrict__ A,
                                                     const short* __restrict__ Bm,
                                                     const float* __restrict__ bias,
                                                     float* __restrict__ Cf,
                                                     short* __restrict__ Cb,
                                                     float* __restrict__ stats,
                                                     int use_bf16) {
    __shared__ short lA[4096];
    __shared__ short lB[4096];
    __shared__ float sml[128][2];
    __shared__ float ssl[128][2];
    const int tid = threadIdx.x;
    const int ctile = blockIdx.x >> 4;          // 0..249  (col tile, slow dim)
    const int row0 = (blockIdx.x & 15) * 128;   // row tile, fast dim
    const int col0 = ctile * 128;
    const int lane = tid & 63;
    const int w = tid >> 6;
    const int wr = w >> 1, wc = w & 1;
    const int g = lane >> 4, rr = lane & 15;

    f32x4 acc[4][4];
    for (int m = 0; m < 4; ++m)
        for (int n = 0; n < 4; ++n)
            for (int q = 0; q < 4; ++q) acc[m][n][q] = 0.f;

    for (int kk = 0; kk < 512; kk += 32) {
        for (int p = 0; p < 2; ++p) {
            int u = p * 256 + tid;
            int kg = u >> 7, r = u & 127;
            gload16(A + (long)(row0 + r) * 512 + kk + kg * 8, &lA[u * 8]);
            gload16(Bm + (long)(col0 + r) * 512 + kk + kg * 8, &lB[u * 8]);
        }
        __syncthreads();
        bf16x8 av[4], bv[4];
        for (int m = 0; m < 4; ++m)
            av[m] = *(const bf16x8*)&lA[(g * 128 + wr * 64 + m * 16 + rr) * 8];
        for (int n = 0; n < 4; ++n)
            bv[n] = *(const bf16x8*)&lB[(g * 128 + wc * 64 + n * 16 + rr) * 8];
        for (int m = 0; m < 4; ++m)
            for (int n = 0; n < 4; ++n)
                acc[m][n] = __builtin_amdgcn_mfma_f32_16x16x32_bf16(av[m], bv[n], acc[m][n], 0, 0, 0);
        __syncthreads();
    }

    float bb[4];
    #pragma unroll
    for (int n = 0; n < 4; ++n) bb[n] = bias[col0 + wc * 64 + n * 16 + rr];

    if (use_bf16) {
        #pragma unroll
        for (int n = 0; n < 4; ++n) {
            int gc = col0 + wc * 64 + n * 16 + rr;
            #pragma unroll
            for (int m = 0; m < 4; ++m) {
                int gr = row0 + wr * 64 + m * 16 + g * 4;
                #pragma unroll
                for (int q = 0; q < 4; ++q)
                    Cb[(long)(gr + q) * Vn + gc] = f2bf(acc[m][n][q] + bb[n]);
            }
        }
    } else {
        #pragma unroll
        for (int n = 0; n < 4; ++n) {
            int gc = col0 + wc * 64 + n * 16 + rr;
            #pragma unroll
            for (int m = 0; m < 4; ++m) {
                int gr = row0 + wr * 64 + m * 16 + g * 4;
                #pragma unroll
                for (int q = 0; q < 4; ++q)
                    Cf[(long)(gr + q) * Vn + gc] = acc[m][n][q] + bb[n];
            }
        }
    }
    #pragma unroll
    for (int m = 0; m < 4; ++m) {
        #pragma unroll
        for (int q = 0; q < 4; ++q) {
            float mx = acc[m][0][q] + bb[0];
            mx = fmaxf(mx, acc[m][1][q] + bb[1]);
            mx = fmaxf(mx, acc[m][2][q] + bb[2]);
            mx = fmaxf(mx, acc[m][3][q] + bb[3]);
            mx = fmaxf(mx, __shfl_xor(mx, 1));
            mx = fmaxf(mx, __shfl_xor(mx, 2));
            mx = fmaxf(mx, __shfl_xor(mx, 4));
            mx = fmaxf(mx, __shfl_xor(mx, 8));
            float s = __expf(acc[m][0][q] + bb[0] - mx) + __expf(acc[m][1][q] + bb[1] - mx)
                    + __expf(acc[m][2][q] + bb[2] - mx) + __expf(acc[m][3][q] + bb[3] - mx);
            s += __shfl_xor(s, 1);
            s += __shfl_xor(s, 2);
            s += __shfl_xor(s, 4);
            s += __shfl_xor(s, 8);
            if (rr == 0) {
                const int r = wr * 64 + m * 16 + g * 4 + q;
                sml[r][wc] = mx; ssl[r][wc] = s;
            }
        }
    }
    __syncthreads();
    if (tid < 128) {
        const float m0 = sml[tid][0], m1 = sml[tid][1];
        const float mm = fmaxf(m0, m1);
        const float ss = ssl[tid][0] * __expf(m0 - mm) + ssl[tid][1] * __expf(m1 - mm);
        float2* sp = (float2*)stats;
        sp[(long)(row0 + tid) * 256 + ctile] = make_float2(mm, ss);
    }
}

// ---------------- per-row lse reduce + subtract (bf16 src -> f32 out, or f32 in-place) ----------------
__global__ __launch_bounds__(256) void k_sub(float* __restrict__ out, const short* __restrict__ Cb,
                                             const float* __restrict__ stats, int use_bf16) {
    const long row = blockIdx.x;
    const int tid = threadIdx.x;
    __shared__ float lse_s;
    if (tid < 64) {
        float m = -__builtin_inff(), s = 0.f;
        for (int tc = tid; tc < 250; tc += 64) {
            const float2 p = ((const float2*)stats)[row * 256 + tc];
            const float nm = fmaxf(m, p.x);
            s = s * __expf(m - nm) + p.y * __expf(p.x - nm);
            m = nm;
        }
        for (int o = 1; o < 64; o <<= 1) {
            const float om = __shfl_xor(m, o), os = __shfl_xor(s, o);
            const float nm = fmaxf(m, om);
            s = s * __expf(m - nm) + os * __expf(om - nm);
            m = nm;
        }
        if (tid == 0) lse_s = m + logf(s);
    }
    __syncthreads();
    const float lse = lse_s;
    float* p = out + row * (long)Vn;
    if (use_bf16) {
        const short* cp = Cb + row * (long)Vn;
        for (int i = tid; i < Vn / 4; i += 256) {
            short4 c = *(const short4*)(cp + i * 4);
            float4 v;
            v.x = bf2f(c.x) - lse; v.y = bf2f(c.y) - lse;
            v.z = bf2f(c.z) - lse; v.w = bf2f(c.w) - lse;
            *(float4*)(p + i * 4) = v;
        }
    } else {
        for (int i = tid; i < Vn / 4; i += 256) {
            float4 v = *(const float4*)(p + i * 4);
            v.x -= lse; v.y -= lse; v.z -= lse; v.w -= lse;
            *(float4*)(p + i * 4) = v;
        }
    }
}

// ---------------- fused two-operand GEMM + tanh, bf16 out:  C = tanh(A1@B1^T + A2@B2^T + bias) ----------------
__global__ __launch_bounds__(256) void k_ho(const short* __restrict__ A1, const short* __restrict__ A2,
                                            const short* __restrict__ B1, const short* __restrict__ B2,
                                            const float* __restrict__ bias, short* __restrict__ C) {
    __shared__ short lA[4096];
    __shared__ short lB[4096];
    const int tid = threadIdx.x;
    const int row0 = blockIdx.y * 128;
    const int col0 = blockIdx.x * 128;
    const int lane = tid & 63;
    const int w = tid >> 6;
    const int wr = w >> 1, wc = w & 1;
    const int g = lane >> 4, rr = lane & 15;

    f32x4 acc[4][4];
    for (int m = 0; m < 4; ++m)
        for (int n = 0; n < 4; ++n)
            for (int q = 0; q < 4; ++q) acc[m][n][q] = 0.f;

    for (int ph = 0; ph < 2; ++ph) {
        const short* A = ph ? A2 : A1;
        const short* Bm = ph ? B2 : B1;
        for (int kk = 0; kk < 512; kk += 32) {
            for (int p = 0; p < 2; ++p) {
                int u = p * 256 + tid;
                int kg = u >> 7, r = u & 127;
                gload16(A + (long)(row0 + r) * 512 + kk + kg * 8, &lA[u * 8]);
                gload16(Bm + (long)(col0 + r) * 512 + kk + kg * 8, &lB[u * 8]);
            }
            __syncthreads();
            bf16x8 av[4], bv[4];
            for (int m = 0; m < 4; ++m)
                av[m] = *(const bf16x8*)&lA[(g * 128 + wr * 64 + m * 16 + rr) * 8];
            for (int n = 0; n < 4; ++n)
                bv[n] = *(const bf16x8*)&lB[(g * 128 + wc * 64 + n * 16 + rr) * 8];
            for (int m = 0; m < 4; ++m)
                for (int n = 0; n < 4; ++n)
                    acc[m][n] = __builtin_amdgcn_mfma_f32_16x16x32_bf16(av[m], bv[n], acc[m][n], 0, 0, 0);
            __syncthreads();
        }
    }

    for (int n = 0; n < 4; ++n) {
        int gc = col0 + wc * 64 + n * 16 + rr;
        float bb = bias[gc];
        for (int m = 0; m < 4; ++m) {
            int gr = row0 + wr * 64 + m * 16 + g * 4;
            for (int q = 0; q < 4; ++q)
                C[(long)(gr + q) * 512 + gc] = f2bf(tanhf(acc[m][n][q] + bb));
        }
    }
}

// ---------------- pure-GRU cooperative recurrence (32 blocks) + W_out convert (blocks 32..543) ----------------
__device__ __forceinline__ void sig_flag(unsigned* slot, unsigned val) {
    asm volatile("s_waitcnt vmcnt(0)" ::: "memory");   // drain this wave's global stores
    __syncthreads();                                   // all waves drained
    if (threadIdx.x == 0)
        __hip_atomic_store(slot, val, __ATOMIC_RELAXED, __HIP_MEMORY_SCOPE_AGENT);
}
__device__ __forceinline__ void wait_flags32(const unsigned* base, unsigned need) {
    if (threadIdx.x < 32) {
        while (__hip_atomic_load(base + threadIdx.x * 32, __ATOMIC_RELAXED, __HIP_MEMORY_SCOPE_AGENT) < need)
            __builtin_amdgcn_s_sleep(1);
    }
    __syncthreads();
}

__global__ __launch_bounds__(512, 1) void k_seq(
    const float* __restrict__ GX, const int* __restrict__ fra,
    const float* __restrict__ h0,
    const short* __restrict__ Whh_b, const float* __restrict__ b_hh,
    short* __restrict__ hn_all,                // [B*T][512] bf16 raw h_new
    unsigned long long* __restrict__ hn_pub,   // [2][32][128] u64 (4xbf16, FROZEN h)
    unsigned* __restrict__ flags,              // [32][32]
    const float* __restrict__ W_out, short* __restrict__ Wout_b)  // side work
{
    __shared__ __align__(16) short h_all[Bn * Hn];   // frozen h, bf16, swizzled (32 KB)
    __shared__ float gh_sl[3 * 16 * 32];             // gh slice (6 KB)
    const int bid = blockIdx.x;
    const int tid = threadIdx.x;

    if (bid >= Bn) {   // ---- side work: convert W_out f32 -> bf16 while recurrence runs
        const long base = (long)(bid - Bn) * (512 * 16);
        #pragma unroll
        for (int it = 0; it < 16; ++it) {
            long i = base + it * 512 + tid;
            if (i < (long)Vn * Hn / 4) {
                const float4 v = *(const float4*)(W_out + i * 4);
                short4 o; o.x = f2bf(v.x); o.y = f2bf(v.y); o.z = f2bf(v.z); o.w = f2bf(v.w);
                *(short4*)(Wout_b + i * 4) = o;
            }
        }
        return;
    }

    const int wv = tid >> 6, lane = tid & 63;
    bf16x8 afr[16];
    if (wv < 6) {          // gate g = wv>>1 (the two n-halves share A data)
        const int g = wv >> 1;
        const int row = g * 512 + bid * 16 + (lane & 15);
        #pragma unroll
        for (int k = 0; k < 16; ++k)
            afr[k] = *(const bf16x8*)(Whh_b + (long)row * 512 + k * 32 + (lane >> 4) * 8);
    }
    // h_all init from h0 (f32 -> bf16, swizzled)
    #pragma unroll
    for (int it = 0; it < 8; ++it) {
        const int idx2 = it * 512 + tid;          // 8B unit: b*128 + ci2
        const int b = idx2 >> 7, ci2 = idx2 & 127;
        const int j0 = ci2 * 4;
        const int soff = b * 512 + ((((ci2 >> 1)) ^ (b & 7)) << 3) + (ci2 & 1) * 4;
        const float4 v = *(const float4*)(h0 + b * 512 + j0);
        unsigned long long pk = (unsigned long long)(unsigned short)f2bf(v.x)
                              | ((unsigned long long)(unsigned short)f2bf(v.y) << 16)
                              | ((unsigned long long)(unsigned short)f2bf(v.z) << 32)
                              | ((unsigned long long)(unsigned short)f2bf(v.w) << 48);
        *(unsigned long long*)&h_all[soff] = pk;
    }

    const int eb = tid >> 4, jj = tid & 15;       // elementwise mapping (batch, slice-col)
    float h_carry = h0[eb * 512 + bid * 16 + jj];
    const int flen_e = fra[eb];
    const int jglob = bid * 16 + jj;
    const float bhr = b_hh[jglob];                // loop-invariant bias hoist
    const float bhz = b_hh[512 + jglob];
    const float bhn = b_hh[1024 + jglob];

    // pipelined staging: this thread's fixed ci2 and its single producer's flag
    const int ci2s = wv * 16 + (lane & 15);       // covers [0,128) across 8 waves
    const unsigned* fp = flags + (ci2s >> 2) * 32;
    const int bbase = lane >> 4;                  // b = bbase + it*4

    for (int t = 0; t < Tn; ++t) {
        // A: prefetch gx slice for step t
        const long base = (long)(eb * Tn + t) * H3 + jglob;
        const float gxr = GX[base];
        const float gxz = GX[base + 512];
        const float gxn = GX[base + 1024];
        // B: poll my producer's flag, then stage my 8 units (frozen h -> no merge)
        if (t >= 1) {
            while (__hip_atomic_load(fp, __ATOMIC_RELAXED, __HIP_MEMORY_SCOPE_AGENT) < (unsigned)t)
                __builtin_amdgcn_s_sleep(1);
            const unsigned long long* src = hn_pub + ((t - 1) & 1) * 4096;
            #pragma unroll
            for (int it = 0; it < 8; ++it) {
                const int b = bbase + it * 4;
                const unsigned long long v =
                    __hip_atomic_load(src + b * 128 + ci2s, __ATOMIC_RELAXED, __HIP_MEMORY_SCOPE_AGENT);
                const int soff = b * 512 + ((((ci2s >> 1)) ^ (b & 7)) << 3) + (ci2s & 1) * 4;
                *(unsigned long long*)&h_all[soff] = v;
            }
        }
        __syncthreads();
        // E1: gh(t) slice (waves 0-5), dual accumulator
        if (wv < 6) {
            const int g = wv >> 1, n = wv & 1;
            const int bq = n * 16 + (lane & 15);
            f32x4 a0 = {0.f, 0.f, 0.f, 0.f}, a1 = {0.f, 0.f, 0.f, 0.f};
            #pragma unroll
            for (int k = 0; k < 8; ++k) {
                const int c0 = k * 4 + (lane >> 4);
                const int c1 = (k + 8) * 4 + (lane >> 4);
                bf16x8 b0 = *(const bf16x8*)&h_all[bq * 512 + ((c0 ^ (bq & 7)) << 3)];
                bf16x8 b1 = *(const bf16x8*)&h_all[bq * 512 + ((c1 ^ (bq & 7)) << 3)];
                a0 = __builtin_amdgcn_mfma_f32_16x16x32_bf16(afr[k], b0, a0, 0, 0, 0);
                a1 = __builtin_amdgcn_mfma_f32_16x16x32_bf16(afr[k + 8], b1, a1, 0, 0, 0);
            }
            const int r0 = (lane >> 4) * 4;
            #pragma unroll
            for (int q = 0; q < 4; ++q)
                gh_sl[g * 512 + (r0 + q) * 32 + bq] = a0[q] + a1[q];
        }
        __syncthreads();
        // G: GRU elementwise (f32 carry) + publish FROZEN h + signal; raw hn_all store in slack
        {
            const float ghr = gh_sl[jj * 32 + eb]          + bhr;
            const float ghz = gh_sl[512 + jj * 32 + eb]    + bhz;
            const float ghn = gh_sl[1024 + jj * 32 + eb]   + bhn;
            const float r = 1.f / (1.f + __expf(-(gxr + ghr)));
            const float z = 1.f / (1.f + __expf(-(gxz + ghz)));
            const float nn = tanhf(gxn + r * ghn);
            const float hv = (1.f - z) * nn + z * h_carry;   // raw h_new (f32)
            h_carry = (t < flen_e) ? hv : h_carry;           // frozen state
            int w32 = (int)(unsigned short)f2bf(h_carry);
            int n1 = __shfl_down(w32, 1);
            int n2 = __shfl_down(w32, 2);
            int n3 = __shfl_down(w32, 3);
            if ((jj & 3) == 0) {
                unsigned long long pk = (unsigned long long)(unsigned)(w32 | (n1 << 16))
                                      | ((unsigned long long)(unsigned)(n2 | (n3 << 16)) << 32);
                __hip_atomic_store(hn_pub + (t & 1) * 4096 + eb * 128 + bid * 4 + (jj >> 2), pk,
                                   __ATOMIC_RELAXED, __HIP_MEMORY_SCOPE_AGENT);
            }
            sig_flag(flags + bid * 32, (unsigned)(t + 1));
            hn_all[(long)(eb * Tn + t) * Hn + jglob] = f2bf(hv);   // raw, slack
        }
    }
}

// ---------------- batched attention: one block per batch b, all 64 steps at once ----------------
__global__ __launch_bounds__(512, 1) void k_attn(
    const float* __restrict__ enc, const short* __restrict__ hn_all,
    const void* __restrict__ maskp, short* __restrict__ ctx_b)
{
    __shared__ __align__(16) short encl[64 * 536];   // enc[b] bf16, rows padded (68.6 KB)
    __shared__ __align__(16) short hnlbuf[64 * 536]; // hn rows / later enct[512][64] swizzled
    __shared__ __align__(16) float scl[64 * 64];     // scores f32 (16 KB)
    __shared__ __align__(16) short albc[64 * 72];    // al bf16 (9.2 KB)
    const int b = blockIdx.x;
    const int tid = threadIdx.x;
    const int wv = tid >> 6, lane = tid & 63;
    const int g = lane >> 4, rr = lane & 15;

    const unsigned w0 = ((const unsigned*)maskp)[0];
    const int mmode = (w0 == 1u) ? 0 : (w0 == 0x3F800000u ? 2 : 1);  // int32 / f32 / byte

    {
        const float* encb = enc + (long)b * (Sn * Hn);
        #pragma unroll
        for (int it = 0; it < 16; ++it) {
            int e = (it * 512 + tid) * 4;
            float4 v = *(const float4*)(encb + e);
            int s = e >> 9, k = e & 511;
            short4 o; o.x = f2bf(v.x); o.y = f2bf(v.y); o.z = f2bf(v.z); o.w = f2bf(v.w);
            *(short4*)(encl + s * 536 + k) = o;
        }
    }
    {
        const short* hb = hn_all + (long)b * (Tn * Hn);
        #pragma unroll
        for (int it = 0; it < 8; ++it) {
            int u = it * 512 + tid;
            int t = u >> 6, k8 = (u & 63) * 8;
            *(int4*)(hnlbuf + t * 536 + k8) = *(const int4*)(hb + t * 512 + k8);
        }
    }
    __syncthreads();

    // scores MFMA: M=64(t) x N=64(s) x K=512
    for (int i = 0; i < 2; ++i) {
        const int id = wv * 2 + i;
        const int tt = id >> 2, ss = id & 3;
        f32x4 a0 = {0.f, 0.f, 0.f, 0.f}, a1 = {0.f, 0.f, 0.f, 0.f};
        #pragma unroll
        for (int k = 0; k < 8; ++k) {
            bf16x8 av0 = *(const bf16x8*)&hnlbuf[(tt * 16 + rr) * 536 + k * 32 + g * 8];
            bf16x8 bv0 = *(const bf16x8*)&encl[(ss * 16 + rr) * 536 + k * 32 + g * 8];
            bf16x8 av1 = *(const bf16x8*)&hnlbuf[(tt * 16 + rr) * 536 + (k + 8) * 32 + g * 8];
            bf16x8 bv1 = *(const bf16x8*)&encl[(ss * 16 + rr) * 536 + (k + 8) * 32 + g * 8];
            a0 = __builtin_amdgcn_mfma_f32_16x16x32_bf16(av0, bv0, a0, 0, 0, 0);
            a1 = __builtin_amdgcn_mfma_f32_16x16x32_bf16(av1, bv1, a1, 0, 0, 0);
        }
        #pragma unroll
        for (int q = 0; q < 4; ++q)
            scl[(tt * 16 + g * 4 + q) * 64 + ss * 16 + rr] = a0[q] + a1[q];
    }
    __syncthreads();

    // softmax per t-row
    {
        const int t = wv * 8 + (lane >> 3);
        const int sub = lane & 7;
        float v[8];
        #pragma unroll
        for (int e = 0; e < 8; ++e) {
            const int s = sub * 8 + e;
            bool mv;
            if (mmode == 0)      mv = ((const int*)maskp)[b * Sn + s] != 0;
            else if (mmode == 1) mv = ((const unsigned char*)maskp)[b * Sn + s] != 0;
            else                 mv = ((const float*)maskp)[b * Sn + s] != 0.f;
            v[e] = mv ? scl[t * 64 + s] : -__builtin_inff();
        }
        float mx = v[0];
        #pragma unroll
        for (int e = 1; e < 8; ++e) mx = fmaxf(mx, v[e]);
        mx = fmaxf(mx, __shfl_xor(mx, 1));
        mx = fmaxf(mx, __shfl_xor(mx, 2));
        mx = fmaxf(mx, __shfl_xor(mx, 4));
        float su = 0.f;
        float ev[8];
        #pragma unroll
        for (int e = 0; e < 8; ++e) { ev[e] = __expf(v[e] - mx); su += ev[e]; }
        su += __shfl_xor(su, 1);
        su += __shfl_xor(su, 2);
        su += __shfl_xor(su, 4);
        const float inv = 1.f / su;
        bf16x8 o;
        #pragma unroll
        for (int e = 0; e < 8; ++e) o[e] = f2bf(ev[e] * inv);
        *(bf16x8*)&albc[t * 72 + sub * 8] = o;
    }
    // transpose encl -> enct[512][64] (chunk-XOR swizzled) in hnlbuf
    {
        short* enct = hnlbuf;
        const int j = tid;
        #pragma unroll
        for (int c = 0; c < 8; ++c) {
            bf16x8 tmp;
            #pragma unroll
            for (int e = 0; e < 8; ++e) tmp[e] = encl[(c * 8 + e) * 536 + j];
            *(bf16x8*)&enct[j * 64 + ((c ^ (j & 7)) * 8)] = tmp;
        }
    }
    __syncthreads();

    // ctx MFMA: M=64(t) x N=512(j) x K=64(s)
    {
        const short* enct = hnlbuf;
        for (int i = 0; i < 16; ++i) {
            const int id = wv * 16 + i;
            const int tt = id >> 5, jt = id & 31;
            const int jr = jt * 16 + rr;
            f32x4 acc = {0.f, 0.f, 0.f, 0.f};
            #pragma unroll
            for (int kk = 0; kk < 2; ++kk) {
                bf16x8 av = *(const bf16x8*)&albc[(tt * 16 + rr) * 72 + kk * 32 + g * 8];
                const int c = kk * 4 + g;
                bf16x8 bv = *(const bf16x8*)&enct[jr * 64 + ((c ^ (jr & 7)) * 8)];
                acc = __builtin_amdgcn_mfma_f32_16x16x32_bf16(av, bv, acc, 0, 0, 0);
            }
            #pragma unroll
            for (int q = 0; q < 4; ++q) {
                const int t = tt * 16 + g * 4 + q;
                ctx_b[(long)(b * Tn + t) * Hn + jr] = f2bf(acc[q]);
            }
        }
    }
}

extern "C" void kernel_launch(void* const* d_in, const int* in_sizes, int n_in,
                              void* d_out, int out_size, void* d_ws, size_t ws_size,
                              hipStream_t stream) {
    const float* enc   = (const float*)d_in[0];
    const float* h0    = (const float*)d_in[1];
    const void*  maskp = d_in[2];
    const int*   tgt   = (const int*)d_in[3];
    const int*   fra   = (const int*)d_in[4];
    const float* emb   = (const float*)d_in[5];
    const float* W_ih  = (const float*)d_in[6];
    const float* W_hh  = (const float*)d_in[7];
    const float* b_ih  = (const float*)d_in[8];
    const float* b_hh  = (const float*)d_in[9];
    const float* W_cc  = (const float*)d_in[10];
    const float* b_cc  = (const float*)d_in[11];
    const float* W_out = (const float*)d_in[12];
    const float* b_out = (const float*)d_in[13];
    float* out = (float*)d_out;

    char* ws = (char*)d_ws;
    float*    GX      = (float*)ws;   ws += (long)2048 * 1536 * 4;  // 12.58 MB
    short*    Xb      = (short*)ws;   ws += (long)2048 * 512 * 2;   //  2.10 MB
    short*    Wih_b   = (short*)ws;   ws += (long)1536 * 512 * 2;   //  1.57 MB
    short*    Wout_b  = (short*)ws;   ws += (long)32000 * 512 * 2;  // 32.77 MB
    short*    Whh_b   = (short*)ws;   ws += (long)1536 * 512 * 2;   //  1.57 MB
    short*    Wc1_b   = (short*)ws;   ws += (long)512 * 512 * 2;    //  0.52 MB
    short*    Wcc2_b  = (short*)ws;   ws += (long)512 * 512 * 2;    //  0.52 MB
    short*    ho_b    = (short*)ws;   ws += (long)2048 * 512 * 2;   //  2.10 MB
    short*    hn_all  = (short*)ws;   ws += (long)2048 * 512 * 2;   //  2.10 MB
    short*    ctx_b   = (short*)ws;   ws += (long)2048 * 512 * 2;   //  2.10 MB
    float*    stats   = (float*)ws;   ws += (long)2048 * 256 * 2 * 4; // 4.19 MB
    unsigned long long* hn_pub = (unsigned long long*)ws; ws += (long)2 * 4096 * 8;   // 64 KB
    unsigned* flags   = (unsigned*)ws; ws += 1024 * 4;              // 4 KB (~62.3 MB so far)
    const long cb_bytes = (long)2048 * Vn * 2;                      // 131 MB bf16 C
    const long used = (long)(ws - (char*)d_ws);
    const int use_bf16 = (ws_size >= (size_t)(used + cb_bytes)) ? 1 : 0;
    short* Cb = use_bf16 ? (short*)ws : nullptr;

    // --- prep (merged converts + gather)
    hipMemsetAsync(flags, 0, 1024 * 4, stream);
    k_prep<<<3072, 256, 0, stream>>>(tgt, emb, W_ih, W_hh, W_cc, Xb, Wih_b, Whh_b, Wc1_b, Wcc2_b);

    // --- GX = X @ W_ih^T + b_ih   (M=2048, N=1536, K=512)
    k_gemm_bf16<<<dim3(12, 16), 256, 0, stream>>>(Xb, 512, Wih_b, 512, b_ih, GX, 1536, 512);

    // --- pure-GRU cooperative recurrence (blocks 0-31) + W_out convert (blocks 32-543)
    k_seq<<<544, 512, 0, stream>>>(GX, fra, h0, Whh_b, b_hh, hn_all, hn_pub, flags, W_out, Wout_b);

    // --- batched attention (one block per batch)
    k_attn<<<32, 512, 0, stream>>>(enc, hn_all, maskp, ctx_b);

    // --- ho = tanh(ctx@Wc1^T + hn@Wc2^T + b_cc) -> bf16
    k_ho<<<dim3(4, 16), 256, 0, stream>>>(ctx_b, hn_all, Wc1_b, Wcc2_b, b_cc, ho_b);

    // --- logits (1D grid, col-tile-major for Wout L2 reuse) + fused lse stats
    k_gemm_logits<<<4000, 256, 0, stream>>>(ho_b, Wout_b, b_out, out, Cb, stats, use_bf16);

    // --- per-row lse reduce + subtract -> f32 d_out
    k_sub<<<2048, 256, 0, stream>>>(out, Cb, stats, use_bf16);
}